// Round 4
// baseline (553.171 us; speedup 1.0000x reference)
//
#include <hip/hip_runtime.h>
#include <hip/hip_bf16.h>

// Problem: B=32, S=4096, D=512.
// out = [att_weights (32,4096) fp32 | hidden_output (32,512) fp32]

typedef __attribute__((ext_vector_type(8))) short bf16x8;
typedef __attribute__((ext_vector_type(4))) float f32x4;

#define BM 128
#define BKK 32
#define LDA 40   // fallback A LDS row: 32 bf16 + 8 pad

static __device__ __forceinline__ unsigned pack2(float a, float b) {
    // RNE fp32->bf16, two at a time, packed into one dword
    unsigned ua = __float_as_uint(a), ub = __float_as_uint(b);
    unsigned ra = (ua + 0x7fffu + ((ua >> 16) & 1u)) >> 16;
    unsigned rb = (ub + 0x7fffu + ((ub >> 16) & 1u)) & 0xffff0000u;
    return ra | rb;
}

static __device__ __forceinline__ float bf2f(short s) {
    return __uint_as_float(((unsigned)(unsigned short)s) << 16);
}

static __device__ __forceinline__ void async_load16(const void* g, void* l) {
    __builtin_amdgcn_global_load_lds(
        (const __attribute__((address_space(1))) void*)g,
        (__attribute__((address_space(3))) void*)l, 16, 0, 0);
}

static __device__ __forceinline__ float fast_tanh(float x) {
    float ex = exp2f(x * 2.8853900817779268f);
    return 1.0f - 2.0f / (ex + 1.0f);
}

// ws layout (bytes):
#define WS_WBF     0L          // 512 KB  Ws bf16 tiled+swizzled
#define WS_EPART   524288L     // 2 MB    4 x 131072 f32
#define WS_E       2621440L    // 512 KB
#define WS_T       3145728L    // 64 KB
#define WS_STATS   3211264L    // 256 B
#define WS_CTXP    3211520L    // 1 MB    16 x 32 x 512 f32
#define WS_SRCBF   4260096L    // 128 MB  src bf16 tiled+swizzled [plan A only]
#define WS_NEED_A  (WS_SRCBF + 134217728L)

// ---- Ws (W[:,512:]) -> bf16, tile-contiguous + bank-swizzled ----
// tile (hx,kt): 128 rows x 32 k; position p=(r,u') stores data unit u'^((r>>1)&3)
__global__ void wconv_kernel(const float* __restrict__ W, short* __restrict__ wbf) {
    const int gid = blockIdx.x * 256 + threadIdx.x;       // [0, 32768)
    const int tile = gid >> 9, p = gid & 511;
    const int hx = tile >> 4, ktile = tile & 15;
    const int r = p >> 2, up = p & 3;
    const int u = up ^ ((r >> 1) & 3);
    const float* s = W + (long)(hx * 128 + r) * 1024 + 512 + ktile * 32 + u * 8;
    float4 v0 = *(const float4*)(s);
    float4 v1 = *(const float4*)(s + 4);
    uint4 pk;
    pk.x = pack2(v0.x, v0.y); pk.y = pack2(v0.z, v0.w);
    pk.z = pack2(v1.x, v1.y); pk.w = pack2(v1.z, v1.w);
    ((uint4*)wbf)[gid] = pk;
}

// ---- src -> bf16, same tiled layout: tile (mt,kt), mt in [0,1024) ----
__global__ void srcconv_kernel(const float* __restrict__ src, short* __restrict__ sbf) {
    const long gid = (long)blockIdx.x * 256 + threadIdx.x;  // [0, 8388608)
    const long tile = gid >> 9;                             // mt*16 + kt
    const int p = (int)(gid & 511);
    const long mt = tile >> 4; const int kt = (int)(tile & 15);
    const int r = p >> 2, up = p & 3;
    const int u = up ^ ((r >> 1) & 3);
    const float* s = src + (mt * 128 + r) * 512 + kt * 32 + u * 8;
    float4 v0 = *(const float4*)(s);
    float4 v1 = *(const float4*)(s + 4);
    uint4 pk;
    pk.x = pack2(v0.x, v0.y); pk.y = pack2(v0.z, v0.w);
    pk.z = pack2(v1.x, v1.y); pk.w = pack2(v1.z, v1.w);
    ((uint4*)sbf)[gid] = pk;
}

// ---- t[b,h] = sum_d targ[b,d] * W[h, d] ----
__global__ void t_kernel(const float* __restrict__ targ,
                         const float* __restrict__ W,
                         float* __restrict__ t) {
    __shared__ float tg[512];
    const int b = blockIdx.x >> 2;
    const int hbase = (blockIdx.x & 3) * 128;
    const int tid = threadIdx.x;
    tg[tid]       = targ[b * 512 + tid];
    tg[tid + 256] = targ[b * 512 + tid + 256];
    __syncthreads();
    const int lane = tid & 63, wave = tid >> 6;
    for (int h = hbase + wave; h < hbase + 128; h += 4) {
        const float* wr = W + (long)h * 1024;
        float s = 0.f;
        #pragma unroll
        for (int i = 0; i < 2; i++) {
            const int d = lane * 4 + i * 256;
            float4 wv = *(const float4*)(wr + d);
            s += wv.x * tg[d] + wv.y * tg[d + 1] + wv.z * tg[d + 2] + wv.w * tg[d + 3];
        }
        s += __shfl_xor(s, 1);  s += __shfl_xor(s, 2);  s += __shfl_xor(s, 4);
        s += __shfl_xor(s, 8);  s += __shfl_xor(s, 16); s += __shfl_xor(s, 32);
        if (lane == 0) t[b * 512 + h] = s;
    }
}

// ---- plan A GEMM: all-async staging from pre-converted bf16 tiles ----
__global__ __launch_bounds__(256, 4)
void gemm_a_kernel(const short* __restrict__ sbf,
                   const short* __restrict__ wbf,
                   const float* __restrict__ t,
                   const float* __restrict__ V,
                   float* __restrict__ epart) {
    __shared__ __align__(16) short As[4096];
    __shared__ __align__(16) short Bs[4096];
    __shared__ float er[2][128];   // [wn][m_local] epilogue cross-wave combine

    const int tid = threadIdx.x;
    const int L = blockIdx.x;
    const int mt = (L >> 5) * 8 + (L & 7);
    const int hx = (L >> 3) & 3;
    const long m0 = (long)mt * BM;
    const int b = (int)(m0 >> 12);

    const int lane = tid & 63;
    const int wave = tid >> 6;
    const int wm = wave & 1, wn = wave >> 1;
    const int lr = lane & 15, quad = lane >> 4;

    f32x4 acc[4][4];
    #pragma unroll
    for (int i = 0; i < 4; i++)
        #pragma unroll
        for (int j = 0; j < 4; j++)
            acc[i][j] = (f32x4){0.f, 0.f, 0.f, 0.f};

    const short* abase = sbf + (long)mt * 16 * 4096;
    const short* bbase = wbf + (long)hx * 16 * 4096;

    for (int kk = 0; kk < 16; kk++) {
        __syncthreads();
        const short* ag = abase + kk * 4096;
        const short* bg = bbase + kk * 4096;
        async_load16(ag + tid * 8, As + tid * 8);
        async_load16(ag + 2048 + tid * 8, As + 2048 + tid * 8);
        async_load16(bg + tid * 8, Bs + tid * 8);
        async_load16(bg + 2048 + tid * 8, Bs + 2048 + tid * 8);
        __syncthreads();   // drains vmcnt (covers global_load_lds)

        bf16x8 af[4], bfr[4];
        #pragma unroll
        for (int mi = 0; mi < 4; mi++) {
            const int row = wm * 64 + mi * 16 + lr;
            const int q = quad ^ ((row >> 1) & 3);
            af[mi] = *(const bf16x8*)(As + row * 32 + q * 8);
        }
        #pragma unroll
        for (int ni = 0; ni < 4; ni++) {
            const int row = wn * 64 + ni * 16 + lr;
            const int q = quad ^ ((row >> 1) & 3);
            bfr[ni] = *(const bf16x8*)(Bs + row * 32 + q * 8);
        }
        #pragma unroll
        for (int mi = 0; mi < 4; mi++)
            #pragma unroll
            for (int ni = 0; ni < 4; ni++)
                acc[mi][ni] = __builtin_amdgcn_mfma_f32_16x16x32_bf16(
                    af[mi], bfr[ni], acc[mi][ni], 0, 0, 0);
    }

    // epilogue: epart[hx][m] = sum over ALL 128 h of this slice.
    // Each wave's lr-reduction yields its wn-half; combine halves via LDS.
    const float* trow = t + b * 512;
    float th[4], vv[4];
    #pragma unroll
    for (int ni = 0; ni < 4; ni++) {
        const int h = hx * 128 + wn * 64 + ni * 16 + lr;
        th[ni] = trow[h];
        vv[ni] = V[h];
    }
    #pragma unroll
    for (int mi = 0; mi < 4; mi++) {
        #pragma unroll
        for (int r = 0; r < 4; r++) {
            float es = 0.f;
            #pragma unroll
            for (int ni = 0; ni < 4; ni++)
                es += fast_tanh(acc[mi][ni][r] + th[ni]) * vv[ni];
            es += __shfl_xor(es, 1);
            es += __shfl_xor(es, 2);
            es += __shfl_xor(es, 4);
            es += __shfl_xor(es, 8);
            if (lr == 0) er[wn][wm * 64 + mi * 16 + quad * 4 + r] = es;
        }
    }
    __syncthreads();
    if (tid < 128)
        epart[(long)hx * 131072 + m0 + tid] = er[0][tid] + er[1][tid];
}

// ---- plan B GEMM (fallback): inline fp32->bf16 A staging ----
__global__ __launch_bounds__(256, 2)
void gemm_b_kernel(const float* __restrict__ src,
                   const short* __restrict__ wbf,
                   const float* __restrict__ t,
                   const float* __restrict__ V,
                   float* __restrict__ epart) {
    __shared__ __align__(16) short As[BM * LDA];
    __shared__ __align__(16) short Bs[4096];
    __shared__ float er[2][128];

    const int tid = threadIdx.x;
    const int L = blockIdx.x;
    const int mt = (L >> 5) * 8 + (L & 7);
    const int hx = (L >> 3) & 3;
    const long m0 = (long)mt * BM;
    const int b = (int)(m0 >> 12);

    const int lane = tid & 63;
    const int wave = tid >> 6;
    const int wm = wave & 1, wn = wave >> 1;
    const int lr = lane & 15, quad = lane >> 4;

    f32x4 acc[4][4];
    #pragma unroll
    for (int i = 0; i < 4; i++)
        #pragma unroll
        for (int j = 0; j < 4; j++)
            acc[i][j] = (f32x4){0.f, 0.f, 0.f, 0.f};

    const int arow = tid >> 1, ah = (tid & 1) * 16;

    for (int kt = 0; kt < 512; kt += BKK) {
        __syncthreads();
        const short* chunk = wbf + (long)(hx * 16 + (kt >> 5)) * 4096;
        async_load16(chunk + tid * 8, Bs + tid * 8);
        async_load16(chunk + 2048 + tid * 8, Bs + 2048 + tid * 8);
        const float* ap = src + (m0 + arow) * 512 + kt + ah;
        float4 v0 = *(const float4*)(ap);
        float4 v1 = *(const float4*)(ap + 4);
        float4 v2 = *(const float4*)(ap + 8);
        float4 v3 = *(const float4*)(ap + 12);
        uint4 pA, pB;
        pA.x = pack2(v0.x, v0.y); pA.y = pack2(v0.z, v0.w);
        pA.z = pack2(v1.x, v1.y); pA.w = pack2(v1.z, v1.w);
        pB.x = pack2(v2.x, v2.y); pB.y = pack2(v2.z, v2.w);
        pB.z = pack2(v3.x, v3.y); pB.w = pack2(v3.z, v3.w);
        *(uint4*)(As + arow * LDA + ah)     = pA;
        *(uint4*)(As + arow * LDA + ah + 8) = pB;
        __syncthreads();

        bf16x8 af[4], bfr[4];
        #pragma unroll
        for (int mi = 0; mi < 4; mi++)
            af[mi] = *(const bf16x8*)(As + (wm * 64 + mi * 16 + lr) * LDA + quad * 8);
        #pragma unroll
        for (int ni = 0; ni < 4; ni++) {
            const int row = wn * 64 + ni * 16 + lr;
            const int q = quad ^ ((row >> 1) & 3);
            bfr[ni] = *(const bf16x8*)(Bs + row * 32 + q * 8);
        }
        #pragma unroll
        for (int mi = 0; mi < 4; mi++)
            #pragma unroll
            for (int ni = 0; ni < 4; ni++)
                acc[mi][ni] = __builtin_amdgcn_mfma_f32_16x16x32_bf16(
                    af[mi], bfr[ni], acc[mi][ni], 0, 0, 0);
    }

    const float* trow = t + b * 512;
    float th[4], vv[4];
    #pragma unroll
    for (int ni = 0; ni < 4; ni++) {
        const int h = hx * 128 + wn * 64 + ni * 16 + lr;
        th[ni] = trow[h];
        vv[ni] = V[h];
    }
    #pragma unroll
    for (int mi = 0; mi < 4; mi++) {
        #pragma unroll
        for (int r = 0; r < 4; r++) {
            float es = 0.f;
            #pragma unroll
            for (int ni = 0; ni < 4; ni++)
                es += fast_tanh(acc[mi][ni][r] + th[ni]) * vv[ni];
            es += __shfl_xor(es, 1);
            es += __shfl_xor(es, 2);
            es += __shfl_xor(es, 4);
            es += __shfl_xor(es, 8);
            if (lr == 0) er[wn][wm * 64 + mi * 16 + quad * 4 + r] = es;
        }
    }
    __syncthreads();
    if (tid < 128)
        epart[(long)hx * 131072 + m0 + tid] = er[0][tid] + er[1][tid];
}

// ---- stats: e = sum of 4 partials; per-b max & expsum ----
__global__ void stats_kernel(const float* __restrict__ epart,
                             float* __restrict__ e, float* __restrict__ stats) {
    const int b = blockIdx.x, tid = threadIdx.x;
    __shared__ float red[256];
    float ev[16];
    float mx = -1e30f;
    #pragma unroll
    for (int i = 0; i < 16; i++) {
        const long m = (long)b * 4096 + tid + i * 256;
        float v = epart[m] + epart[131072 + m] + epart[262144 + m] + epart[393216 + m];
        e[m] = v;
        ev[i] = v;
        mx = fmaxf(mx, v);
    }
    red[tid] = mx; __syncthreads();
    for (int st = 128; st > 0; st >>= 1) {
        if (tid < st) red[tid] = fmaxf(red[tid], red[tid + st]);
        __syncthreads();
    }
    mx = red[0]; __syncthreads();
    float sm = 0.f;
    #pragma unroll
    for (int i = 0; i < 16; i++)
        sm += exp2f((ev[i] - mx) * 1.4426950408889634f);
    red[tid] = sm; __syncthreads();
    for (int st = 128; st > 0; st >>= 1) {
        if (tid < st) red[tid] += red[tid + st];
        __syncthreads();
    }
    if (tid == 0) { stats[b * 2] = mx; stats[b * 2 + 1] = red[0]; }
}

// ---- plan A ctx: att write + weighted sum over bf16 tiled src ----
__global__ __launch_bounds__(256)
void ctx_bf_kernel(const float* __restrict__ e, const float* __restrict__ stats,
                   const float* __restrict__ mask, const short* __restrict__ sbf,
                   float* __restrict__ att, float* __restrict__ ctxpart) {
    const int b = blockIdx.y;
    const int s0 = blockIdx.x * 256;
    const int tid = threadIdx.x;
    __shared__ float ash[256];
    __shared__ float part[4][512];

    const float mx = stats[b * 2];
    const float inv = 1.0f / stats[b * 2 + 1];
    const int s = s0 + tid;
    float a = exp2f((e[b * 4096 + s] - mx) * 1.4426950408889634f) * inv
              * mask[b * 4096 + s];
    att[(long)b * 4096 + s] = a;
    ash[tid] = a;
    __syncthreads();

    const int phase = tid >> 6, uu = tid & 63;
    const int kt = uu >> 2, u = uu & 3;
    const long mt0 = ((long)b * 4096 + s0) >> 7;
    float acc[8];
    #pragma unroll
    for (int j = 0; j < 8; j++) acc[j] = 0.f;

    for (int i = phase; i < 256; i += 4) {
        const long mt = mt0 + (i >> 7);
        const int r = i & 127;
        const short* p = sbf + (mt * 16 + kt) * 4096 + r * 32 + ((u ^ ((r >> 1) & 3))) * 8;
        bf16x8 v = *(const bf16x8*)p;
        const float w = ash[i];
        #pragma unroll
        for (int j = 0; j < 8; j++) acc[j] += w * bf2f(v[j]);
    }
    #pragma unroll
    for (int j = 0; j < 8; j++) part[phase][uu * 8 + j] = acc[j];
    __syncthreads();
    for (int d = tid; d < 512; d += 256) {
        float sv = part[0][d] + part[1][d] + part[2][d] + part[3][d];
        ctxpart[((long)blockIdx.x * 32 + b) * 512 + d] = sv;
    }
}

// ---- plan B ctx: fp32 src ----
__global__ __launch_bounds__(256)
void ctx_f32_kernel(const float* __restrict__ e, const float* __restrict__ stats,
                    const float* __restrict__ mask, const float* __restrict__ src,
                    float* __restrict__ att, float* __restrict__ ctxpart) {
    const int b = blockIdx.y;
    const int s0 = blockIdx.x * 256;
    const int tid = threadIdx.x;
    __shared__ float ash[256];
    __shared__ float4 part[128];

    const float mx = stats[b * 2];
    const float inv = 1.0f / stats[b * 2 + 1];
    const int s = s0 + tid;
    float a = exp2f((e[b * 4096 + s] - mx) * 1.4426950408889634f) * inv
              * mask[b * 4096 + s];
    att[(long)b * 4096 + s] = a;
    ash[tid] = a;
    __syncthreads();

    const int half = tid >> 7, d4 = tid & 127;
    float4 acc = {0.f, 0.f, 0.f, 0.f};
    const float4* s4 = (const float4*)(src + ((long)b * 4096 + s0) * 512);
    #pragma unroll 4
    for (int i = half; i < 256; i += 2) {
        float4 v = s4[(long)i * 128 + d4];
        float w = ash[i];
        acc.x += w * v.x; acc.y += w * v.y; acc.z += w * v.z; acc.w += w * v.w;
    }
    if (half) part[d4] = acc;
    __syncthreads();
    if (!half) {
        float4 p = part[d4];
        acc.x += p.x; acc.y += p.y; acc.z += p.z; acc.w += p.w;
        *(float4*)(ctxpart + ((long)blockIdx.x * 32 + b) * 512 + d4 * 4) = acc;
    }
}

// ---- final: outh = targ + sum_x ctxpart[x] ----
__global__ void final_kernel(const float* __restrict__ targ,
                             const float* __restrict__ ctxpart,
                             float* __restrict__ outh) {
    const int g = blockIdx.x * 256 + threadIdx.x;   // [0, 16384)
    float sv = targ[g];
    #pragma unroll
    for (int x = 0; x < 16; x++) sv += ctxpart[(long)x * 16384 + g];
    outh[g] = sv;
}

extern "C" void kernel_launch(void* const* d_in, const int* in_sizes, int n_in,
                              void* d_out, int out_size, void* d_ws, size_t ws_size,
                              hipStream_t stream) {
    const float* targ = (const float*)d_in[0];
    const float* src  = (const float*)d_in[1];
    const float* mask = (const float*)d_in[2];
    const float* W    = (const float*)d_in[3];
    const float* V    = (const float*)d_in[4];

    float* att  = (float*)d_out;
    float* outh = (float*)d_out + 131072;

    char* ws = (char*)d_ws;
    short* wbf    = (short*)(ws + WS_WBF);
    float* epart  = (float*)(ws + WS_EPART);
    float* e      = (float*)(ws + WS_E);
    float* t      = (float*)(ws + WS_T);
    float* st     = (float*)(ws + WS_STATS);
    float* ctxp   = (float*)(ws + WS_CTXP);
    short* sbf    = (short*)(ws + WS_SRCBF);

    const bool planA = ws_size >= (size_t)WS_NEED_A;

    if (planA) srcconv_kernel<<<32768, 256, 0, stream>>>(src, sbf);
    wconv_kernel<<<128, 256, 0, stream>>>(W, wbf);
    t_kernel<<<128, 256, 0, stream>>>(targ, W, t);
    if (planA)
        gemm_a_kernel<<<4096, 256, 0, stream>>>(sbf, wbf, t, V, epart);
    else
        gemm_b_kernel<<<4096, 256, 0, stream>>>(src, wbf, t, V, epart);
    stats_kernel<<<32, 256, 0, stream>>>(epart, e, st);
    if (planA)
        ctx_bf_kernel<<<dim3(16, 32), 256, 0, stream>>>(e, st, mask, sbf, att, ctxp);
    else
        ctx_f32_kernel<<<dim3(16, 32), 256, 0, stream>>>(e, st, mask, src, att, ctxp);
    final_kernel<<<64, 256, 0, stream>>>(targ, ctxp, outh);
}

// Round 5
// 494.887 us; speedup vs baseline: 1.1178x; 1.1178x over previous
//
#include <hip/hip_runtime.h>
#include <hip/hip_bf16.h>

// Problem: B=32, S=4096, D=512.
// out = [att_weights (32,4096) fp32 | hidden_output (32,512) fp32]

typedef __attribute__((ext_vector_type(8))) short bf16x8;
typedef __attribute__((ext_vector_type(4))) float f32x4;

#define BM 128
#define BKK 32
#define LDA 40   // A LDS row: 32 bf16 + 8 pad

// packed fp32x2 -> bf16x2 (RNE); lowers to v_cvt_pk_bf16_f32 on gfx950
static __device__ __forceinline__ unsigned cvt2(float a, float b) {
    union { __hip_bfloat162 h; unsigned u; } v;
    v.h = __float22bfloat162_rn(make_float2(a, b));
    return v.u;
}

static __device__ __forceinline__ void async_load16(const void* g, void* l) {
    __builtin_amdgcn_global_load_lds(
        (const __attribute__((address_space(1))) void*)g,
        (__attribute__((address_space(3))) void*)l, 16, 0, 0);
}

static __device__ __forceinline__ float fast_tanh(float x) {
    float ex = exp2f(x * 2.8853900817779268f);
    return 1.0f - 2.0f / (ex + 1.0f);
}

// ws layout (bytes):
#define WS_WBF     0L          // 512 KB  Ws bf16 tiled+swizzled
#define WS_EPART   524288L     // 2 MB    4 x 131072 f32
#define WS_E       2621440L    // 512 KB
#define WS_T       3145728L    // 64 KB
#define WS_STATS   3211264L    // 256 B
#define WS_CTXP    3211520L    // 1 MB    16 x 32 x 512 f32

// ---- Ws (W[:,512:]) -> bf16, tile-contiguous + bank-swizzled ----
// tile (hx,kt): 128 rows x 32 k; position p=(r,u') stores data unit u'^((r>>1)&3)
__global__ void wconv_kernel(const float* __restrict__ W, short* __restrict__ wbf) {
    const int gid = blockIdx.x * 256 + threadIdx.x;       // [0, 32768)
    const int tile = gid >> 9, p = gid & 511;
    const int hx = tile >> 4, ktile = tile & 15;
    const int r = p >> 2, up = p & 3;
    const int u = up ^ ((r >> 1) & 3);
    const float* s = W + (long)(hx * 128 + r) * 1024 + 512 + ktile * 32 + u * 8;
    float4 v0 = *(const float4*)(s);
    float4 v1 = *(const float4*)(s + 4);
    uint4 pk;
    pk.x = cvt2(v0.x, v0.y); pk.y = cvt2(v0.z, v0.w);
    pk.z = cvt2(v1.x, v1.y); pk.w = cvt2(v1.z, v1.w);
    ((uint4*)wbf)[gid] = pk;
}

// ---- t[b,h] = sum_d targ[b,d] * W[h, d] ----
__global__ void t_kernel(const float* __restrict__ targ,
                         const float* __restrict__ W,
                         float* __restrict__ t) {
    __shared__ float tg[512];
    const int b = blockIdx.x >> 2;
    const int hbase = (blockIdx.x & 3) * 128;
    const int tid = threadIdx.x;
    tg[tid]       = targ[b * 512 + tid];
    tg[tid + 256] = targ[b * 512 + tid + 256];
    __syncthreads();
    const int lane = tid & 63, wave = tid >> 6;
    for (int h = hbase + wave; h < hbase + 128; h += 4) {
        const float* wr = W + (long)h * 1024;
        float s = 0.f;
        #pragma unroll
        for (int i = 0; i < 2; i++) {
            const int d = lane * 4 + i * 256;
            float4 wv = *(const float4*)(wr + d);
            s += wv.x * tg[d] + wv.y * tg[d + 1] + wv.z * tg[d + 2] + wv.w * tg[d + 3];
        }
        s += __shfl_xor(s, 1);  s += __shfl_xor(s, 2);  s += __shfl_xor(s, 4);
        s += __shfl_xor(s, 8);  s += __shfl_xor(s, 16); s += __shfl_xor(s, 32);
        if (lane == 0) t[b * 512 + h] = s;
    }
}

// ---- GEMM: A staged inline fp32->bf16 (HW packed cvt), B async from wbf ----
__global__ __launch_bounds__(256, 2)
void gemm_kernel(const float* __restrict__ src,
                 const short* __restrict__ wbf,
                 const float* __restrict__ t,
                 const float* __restrict__ V,
                 float* __restrict__ epart) {
    __shared__ __align__(16) short As[BM * LDA];
    __shared__ __align__(16) short Bs[4096];
    __shared__ float er[2][128];

    const int tid = threadIdx.x;
    const int L = blockIdx.x;
    const int mt = (L >> 5) * 8 + (L & 7);   // XCD swizzle: 4 hx of one mt share an XCD
    const int hx = (L >> 3) & 3;
    const long m0 = (long)mt * BM;
    const int b = (int)(m0 >> 12);

    const int lane = tid & 63;
    const int wave = tid >> 6;
    const int wm = wave & 1, wn = wave >> 1;
    const int lr = lane & 15, quad = lane >> 4;

    f32x4 acc[4][4];
    #pragma unroll
    for (int i = 0; i < 4; i++)
        #pragma unroll
        for (int j = 0; j < 4; j++)
            acc[i][j] = (f32x4){0.f, 0.f, 0.f, 0.f};

    const int arow = tid >> 1, ah = (tid & 1) * 16;

    for (int kt = 0; kt < 512; kt += BKK) {
        __syncthreads();
        // B tile: pre-swizzled bf16 -> direct async to LDS
        const short* chunk = wbf + (long)(hx * 16 + (kt >> 5)) * 4096;
        async_load16(chunk + tid * 8, Bs + tid * 8);
        async_load16(chunk + 2048 + tid * 8, Bs + 2048 + tid * 8);
        // A tile: fp32 load + HW packed cvt + 2x ds_write_b128
        const float* ap = src + (m0 + arow) * 512 + kt + ah;
        float4 v0 = *(const float4*)(ap);
        float4 v1 = *(const float4*)(ap + 4);
        float4 v2 = *(const float4*)(ap + 8);
        float4 v3 = *(const float4*)(ap + 12);
        uint4 pA, pB;
        pA.x = cvt2(v0.x, v0.y); pA.y = cvt2(v0.z, v0.w);
        pA.z = cvt2(v1.x, v1.y); pA.w = cvt2(v1.z, v1.w);
        pB.x = cvt2(v2.x, v2.y); pB.y = cvt2(v2.z, v2.w);
        pB.z = cvt2(v3.x, v3.y); pB.w = cvt2(v3.z, v3.w);
        *(uint4*)(As + arow * LDA + ah)     = pA;
        *(uint4*)(As + arow * LDA + ah + 8) = pB;
        __syncthreads();   // drains vmcnt (covers global_load_lds)

        bf16x8 af[4], bfr[4];
        #pragma unroll
        for (int mi = 0; mi < 4; mi++)
            af[mi] = *(const bf16x8*)(As + (wm * 64 + mi * 16 + lr) * LDA + quad * 8);
        #pragma unroll
        for (int ni = 0; ni < 4; ni++) {
            const int row = wn * 64 + ni * 16 + lr;
            const int q = quad ^ ((row >> 1) & 3);
            bfr[ni] = *(const bf16x8*)(Bs + row * 32 + q * 8);
        }
        #pragma unroll
        for (int mi = 0; mi < 4; mi++)
            #pragma unroll
            for (int ni = 0; ni < 4; ni++)
                acc[mi][ni] = __builtin_amdgcn_mfma_f32_16x16x32_bf16(
                    af[mi], bfr[ni], acc[mi][ni], 0, 0, 0);
    }

    // epilogue: epart[hx][m] = sum over this slice's 128 h of tanh(acc+t)*V
    // C/D layout: col = lane&15, row = quad*4 + reg; combine wn halves via LDS
    const float* trow = t + b * 512;
    float th[4], vv[4];
    #pragma unroll
    for (int ni = 0; ni < 4; ni++) {
        const int h = hx * 128 + wn * 64 + ni * 16 + lr;
        th[ni] = trow[h];
        vv[ni] = V[h];
    }
    #pragma unroll
    for (int mi = 0; mi < 4; mi++) {
        #pragma unroll
        for (int r = 0; r < 4; r++) {
            float es = 0.f;
            #pragma unroll
            for (int ni = 0; ni < 4; ni++)
                es += fast_tanh(acc[mi][ni][r] + th[ni]) * vv[ni];
            es += __shfl_xor(es, 1);
            es += __shfl_xor(es, 2);
            es += __shfl_xor(es, 4);
            es += __shfl_xor(es, 8);
            if (lr == 0) er[wn][wm * 64 + mi * 16 + quad * 4 + r] = es;
        }
    }
    __syncthreads();
    if (tid < 128)
        epart[(long)hx * 131072 + m0 + tid] = er[0][tid] + er[1][tid];
}

// ---- stats: e = sum of 4 partials; per-b max & expsum ----
__global__ void stats_kernel(const float* __restrict__ epart,
                             float* __restrict__ e, float* __restrict__ stats) {
    const int b = blockIdx.x, tid = threadIdx.x;
    __shared__ float red[256];
    float ev[16];
    float mx = -1e30f;
    #pragma unroll
    for (int i = 0; i < 16; i++) {
        const long m = (long)b * 4096 + tid + i * 256;
        float v = epart[m] + epart[131072 + m] + epart[262144 + m] + epart[393216 + m];
        e[m] = v;
        ev[i] = v;
        mx = fmaxf(mx, v);
    }
    red[tid] = mx; __syncthreads();
    for (int st = 128; st > 0; st >>= 1) {
        if (tid < st) red[tid] = fmaxf(red[tid], red[tid + st]);
        __syncthreads();
    }
    mx = red[0]; __syncthreads();
    float sm = 0.f;
    #pragma unroll
    for (int i = 0; i < 16; i++)
        sm += exp2f((ev[i] - mx) * 1.4426950408889634f);
    red[tid] = sm; __syncthreads();
    for (int st = 128; st > 0; st >>= 1) {
        if (tid < st) red[tid] += red[tid + st];
        __syncthreads();
    }
    if (tid == 0) { stats[b * 2] = mx; stats[b * 2 + 1] = red[0]; }
}

// ---- ctx: att write + weighted row-sum of fp32 src -> per-block partials ----
__global__ __launch_bounds__(256)
void ctx_kernel(const float* __restrict__ e, const float* __restrict__ stats,
                const float* __restrict__ mask, const float* __restrict__ src,
                float* __restrict__ att, float* __restrict__ ctxpart) {
    const int b = blockIdx.y;
    const int s0 = blockIdx.x * 256;
    const int tid = threadIdx.x;
    __shared__ float ash[256];
    __shared__ float4 part[128];

    const float mx = stats[b * 2];
    const float inv = 1.0f / stats[b * 2 + 1];
    const int s = s0 + tid;
    float a = exp2f((e[b * 4096 + s] - mx) * 1.4426950408889634f) * inv
              * mask[b * 4096 + s];
    att[(long)b * 4096 + s] = a;
    ash[tid] = a;
    __syncthreads();

    const int half = tid >> 7, d4 = tid & 127;
    float4 acc = {0.f, 0.f, 0.f, 0.f};
    const float4* s4 = (const float4*)(src + ((long)b * 4096 + s0) * 512);
    #pragma unroll 4
    for (int i = half; i < 256; i += 2) {
        float4 v = s4[(long)i * 128 + d4];
        float w = ash[i];
        acc.x += w * v.x; acc.y += w * v.y; acc.z += w * v.z; acc.w += w * v.w;
    }
    if (half) part[d4] = acc;
    __syncthreads();
    if (!half) {
        float4 p = part[d4];
        acc.x += p.x; acc.y += p.y; acc.z += p.z; acc.w += p.w;
        *(float4*)(ctxpart + ((long)blockIdx.x * 32 + b) * 512 + d4 * 4) = acc;
    }
}

// ---- final: outh = targ + sum_x ctxpart[x] ----
__global__ void final_kernel(const float* __restrict__ targ,
                             const float* __restrict__ ctxpart,
                             float* __restrict__ outh) {
    const int g = blockIdx.x * 256 + threadIdx.x;   // [0, 16384)
    float sv = targ[g];
    #pragma unroll
    for (int x = 0; x < 16; x++) sv += ctxpart[(long)x * 16384 + g];
    outh[g] = sv;
}

extern "C" void kernel_launch(void* const* d_in, const int* in_sizes, int n_in,
                              void* d_out, int out_size, void* d_ws, size_t ws_size,
                              hipStream_t stream) {
    const float* targ = (const float*)d_in[0];
    const float* src  = (const float*)d_in[1];
    const float* mask = (const float*)d_in[2];
    const float* W    = (const float*)d_in[3];
    const float* V    = (const float*)d_in[4];

    float* att  = (float*)d_out;
    float* outh = (float*)d_out + 131072;

    char* ws = (char*)d_ws;
    short* wbf    = (short*)(ws + WS_WBF);
    float* epart  = (float*)(ws + WS_EPART);
    float* e      = (float*)(ws + WS_E);
    float* t      = (float*)(ws + WS_T);
    float* st     = (float*)(ws + WS_STATS);
    float* ctxp   = (float*)(ws + WS_CTXP);

    wconv_kernel<<<128, 256, 0, stream>>>(W, wbf);
    t_kernel<<<128, 256, 0, stream>>>(targ, W, t);
    gemm_kernel<<<4096, 256, 0, stream>>>(src, wbf, t, V, epart);
    stats_kernel<<<32, 256, 0, stream>>>(epart, e, st);
    ctx_kernel<<<dim3(16, 32), 256, 0, stream>>>(e, st, mask, src, att, ctxp);
    final_kernel<<<64, 256, 0, stream>>>(targ, ctxp, outh);
}